// Round 10
// baseline (178.522 us; speedup 1.0000x reference)
//
#include <hip/hip_runtime.h>

// CIN forward: B=2048, F=32, DIM=64, layers (128,128)
// out[b, 0:64]   = sum_d relu(W0 @ z0 + b0)[64:128, d]
// out[b, 64:192] = sum_d relu(W1 @ z1 + b1)[0:128, d]
// z0[h*32+m, d] = x[h,d]*x[m,d]   (h,m in [0,32))
// z1[h*32+m, d] = h1[h,d]*x[m,d]  (h in [0,64), m in [0,32)), h1 = layer0 rows 0..63
//
// R10: 32x32x16 MFMA, done right this time. Evidence: R4..R9 all null/negative
// around a 53-56% MfmaUtil plateau with 16x16 (pipe work fixed 119K cyc/CU).
// 32x32 rate is 2382 vs 2075 TF (m06) -> floor 42.8us vs 49.7us, and halves
// MFMA issue slots (8 per K-32 per wave). R3's 32x32 failure was 2 chains with
// back-to-back accumulation; here: 4 independent chains (2 A-frags x 2
// d-groups), chain re-hit distance 4. R3 passed correctness -> layouts are
// HW-verified. Shell = R5c (best measured: rotation+clamp, 2 batches, 256thr).
//
// 32x32x16 f16 fragments (verified by R3 pass):
//   A (32x16): row = lane&31, k = (lane>>5)*8 + j   (8 f16/lane)
//   B (16x32): col = lane&31, k = (lane>>5)*8 + j
//   C/D:       col = lane&31, row = (reg&3) + 8*(reg>>2) + 4*(lane>>5)
//
// B-operand trick: col = d now spans lanes, so the x m-part is K-INVARIANT:
//   xw[g][q][j] = x[q*16 + hi*8 + j][g*32 + d0]   (4 v8h, loaded once)
//   bfr[g](step q) = splat(x_or_h1[h][g*32+d0]) * xw[g][q]
//
// A-frag swizzle: wsw[ks*2048 + s*512 + lane*8 + j]
//   = W[(s*32 + (lane&31))*K + ks*16 + (lane>>5)*8 + j]   (ks = K-16 step)

#define BATCH 2048
#define FSZ   32
#define DIM   64
#define K0    1024
#define K1    2048
#define OUTC  192

#define W0_ELEMS (128 * K0)            // 131072 f16
#define W1_ELEMS (128 * K1)            // 262144 f16
#define TOT_ELEMS (W0_ELEMS + W1_ELEMS)
#define CVT_THREADS (TOT_ELEMS / 4)    // 98304 -> 384 blocks

typedef _Float16 v8h __attribute__((ext_vector_type(8)));
typedef _Float16 v2h __attribute__((ext_vector_type(2)));
typedef float    v16f __attribute__((ext_vector_type(16)));

#define XT_PITCH 40   // xT[d][m]: 80B rows, 16B-aligned v8h loads

// One thread per 4 output f16: coalesced 8B stores, aligned float4 reads.
// Decode e: j0 = e&7, lane = (e>>3)&63, s = (e>>9)&3, ks = e>>11.
__global__ void convert_w_kernel(const float* __restrict__ W0,
                                 const float* __restrict__ W1,
                                 _Float16* __restrict__ wsw) {
    int t = blockIdx.x * blockDim.x + threadIdx.x;
    if (t >= CVT_THREADS) return;
    int e = t * 4;
    const float* src;
    _Float16* dst;
    if (e < W0_ELEMS) {
        int j0 = e & 7, lane = (e >> 3) & 63, s = (e >> 9) & 3, ks = e >> 11;
        src = W0 + (size_t)(s * 32 + (lane & 31)) * K0
                 + ks * 16 + (lane >> 5) * 8 + j0;
        dst = wsw + e;
    } else {
        int u = e - W0_ELEMS;
        int j0 = u & 7, lane = (u >> 3) & 63, s = (u >> 9) & 3, ks = u >> 11;
        src = W1 + (size_t)(s * 32 + (lane & 31)) * K1
                 + ks * 16 + (lane >> 5) * 8 + j0;
        dst = wsw + W0_ELEMS + u;
    }
    float4 v = *(const float4*)src;
    dst[0] = (_Float16)v.x;
    dst[1] = (_Float16)v.y;
    dst[2] = (_Float16)v.z;
    dst[3] = (_Float16)v.w;
}

__device__ __forceinline__ v16f mfma32(v8h a, v8h b, v16f c) {
    return __builtin_amdgcn_mfma_f32_32x32x16_f16(a, b, c, 0, 0, 0);
}

__global__ __launch_bounds__(256, 4) void cin_kernel(
    const float* __restrict__ X,      // (B, 32, 64) fp32
    const float* __restrict__ b0,     // (128,)
    const float* __restrict__ b1,     // (128,)
    const _Float16* __restrict__ Wsw, // swizzled W0 then W1 (f16)
    float* __restrict__ out)          // (B, 192) fp32
{
    __shared__ _Float16 xT[2][DIM * XT_PITCH];  // xT[p][d][m]        (10240 B)
    __shared__ _Float16 xP[2][FSZ * 64];        // xP[p][m][c*2+g]    ( 8192 B)
    __shared__ _Float16 h1P[2][64 * 64];        // h1P[p][h][c*2+g]   (16384 B)

    const int b0i  = blockIdx.x * 2;
    const int tid  = threadIdx.x;
    const int wave = tid >> 6;
    const int lane = tid & 63;
    const int p    = wave & 1;        // batch member
    const int rh   = wave >> 1;       // row half (64 rows = 2 A-frags)
    const int d0   = lane & 31;
    const int hi   = lane >> 5;

    // ---- stage both batches' x -> LDS (xT + packed xP) ----
    #pragma unroll
    for (int i = 0; i < 4; ++i) {
        int idx = tid + i * 256;               // float4 index 0..1023
        int pp = idx >> 9, r4 = idx & 511;
        float4 v = *(const float4*)(X + (size_t)(b0i + pp) * (FSZ * DIM) + r4 * 4);
        int m = (r4 * 4) >> 6, d = (r4 * 4) & 63;
        int g = d >> 5, c = d & 31;            // constant within the float4
        _Float16 f0 = (_Float16)v.x, f1 = (_Float16)v.y,
                 f2 = (_Float16)v.z, f3 = (_Float16)v.w;
        xT[pp][(d + 0) * XT_PITCH + m] = f0;
        xT[pp][(d + 1) * XT_PITCH + m] = f1;
        xT[pp][(d + 2) * XT_PITCH + m] = f2;
        xT[pp][(d + 3) * XT_PITCH + m] = f3;
        xP[pp][m * 64 + (c + 0) * 2 + g] = f0;
        xP[pp][m * 64 + (c + 1) * 2 + g] = f1;
        xP[pp][m * 64 + (c + 2) * 2 + g] = f2;
        xP[pp][m * 64 + (c + 3) * 2 + g] = f3;
    }
    __syncthreads();

    // K-invariant x m-parts of B fragments:
    //   xw[g][q][j] = x[q*16 + hi*8 + j][g*32 + d0]
    v8h xw[2][2];
    #pragma unroll
    for (int g = 0; g < 2; ++g)
        #pragma unroll
        for (int q = 0; q < 2; ++q)
            xw[g][q] = *(const v8h*)(&xT[p][(g * 32 + d0) * XT_PITCH + q * 16 + hi * 8]);

    const _Float16* Wb0 = Wsw + (size_t)rh * 1024 + (size_t)lane * 8;
    const _Float16* Wb1 = Wb0 + W0_ELEMS;
    const _Float16* xPp = &xP[p][d0 * 2];
    const _Float16* hPp = &h1P[p][d0 * 2];

    // ================= layer 0 (32 K-32 iters) =================
    v16f acc[2][2];   // [A-frag sl][d-group g] — 4 independent chains
    acc[0][0] = (v16f)0.0f; acc[0][1] = (v16f)0.0f;
    acc[1][0] = (v16f)0.0f; acc[1][1] = (v16f)0.0f;

    {
        v8h A0, A1, A2, A3, N0, N1, N2, N3;   // frags: even{sl0,sl1}, odd{sl0,sl1}
        v2h svC, svN;
        A0 = *(const v8h*)(Wb0);        A1 = *(const v8h*)(Wb0 + 512);
        A2 = *(const v8h*)(Wb0 + 2048); A3 = *(const v8h*)(Wb0 + 2560);
        svC = *(const v2h*)(xPp);       // h = 0
        #pragma unroll 1
        for (int i = 0; i < 32; ++i) {
            const int kn = (i + 1) & 31;           // clamped prefetch (last unused)
            const _Float16* Wn = Wb0 + (size_t)kn * 4096;
            N0 = *(const v8h*)(Wn);        N1 = *(const v8h*)(Wn + 512);
            N2 = *(const v8h*)(Wn + 2048); N3 = *(const v8h*)(Wn + 2560);
            svN = *(const v2h*)(xPp + kn * 64);
            _Float16 s0 = svC[0], s1 = svC[1];
            v8h s08 = {s0, s0, s0, s0, s0, s0, s0, s0};
            v8h s18 = {s1, s1, s1, s1, s1, s1, s1, s1};
            // step even (q=0)
            v8h be0 = s08 * xw[0][0];
            v8h be1 = s18 * xw[1][0];
            acc[0][0] = mfma32(A0, be0, acc[0][0]);
            acc[1][0] = mfma32(A1, be0, acc[1][0]);
            acc[0][1] = mfma32(A0, be1, acc[0][1]);
            acc[1][1] = mfma32(A1, be1, acc[1][1]);
            // step odd (q=1)
            v8h bo0 = s08 * xw[0][1];
            v8h bo1 = s18 * xw[1][1];
            acc[0][0] = mfma32(A2, bo0, acc[0][0]);
            acc[1][0] = mfma32(A3, bo0, acc[1][0]);
            acc[0][1] = mfma32(A2, bo1, acc[0][1]);
            acc[1][1] = mfma32(A3, bo1, acc[1][1]);
            A0 = N0; A1 = N1; A2 = N2; A3 = N3;
            svC = svN;
        }
    }

    // ---- epilogue 0 ----
    // rh=0: rows 0..63 -> h1P[p] (v2h packed); rh=1: rows 64..127 -> out[b,o-64]
    if (rh == 0) {
        #pragma unroll
        for (int sl = 0; sl < 2; ++sl) {
            #pragma unroll
            for (int reg = 0; reg < 16; ++reg) {
                const int o = sl * 32 + (reg & 3) + 8 * (reg >> 2) + 4 * hi;
                const float bias = b0[o];
                float v0 = acc[sl][0][reg] + bias; v0 = v0 > 0.0f ? v0 : 0.0f;
                float v1 = acc[sl][1][reg] + bias; v1 = v1 > 0.0f ? v1 : 0.0f;
                v2h pk = {(_Float16)v0, (_Float16)v1};
                *(v2h*)(&h1P[p][o * 64 + d0 * 2]) = pk;
            }
        }
    } else {
        #pragma unroll
        for (int sl = 0; sl < 2; ++sl) {
            #pragma unroll
            for (int reg = 0; reg < 16; ++reg) {
                const int o = 64 + sl * 32 + (reg & 3) + 8 * (reg >> 2) + 4 * hi;
                const float bias = b0[o];
                float v0 = acc[sl][0][reg] + bias; v0 = v0 > 0.0f ? v0 : 0.0f;
                float v1 = acc[sl][1][reg] + bias; v1 = v1 > 0.0f ? v1 : 0.0f;
                float s = v0 + v1;
                s += __shfl_xor(s, 1);
                s += __shfl_xor(s, 2);
                s += __shfl_xor(s, 4);
                s += __shfl_xor(s, 8);
                s += __shfl_xor(s, 16);
                if (d0 == 0) out[(size_t)(b0i + p) * OUTC + (o - 64)] = s;
            }
        }
    }
    __syncthreads();   // h1P visible to all waves

    // ================= layer 1 (64 K-32 iters) =================
    acc[0][0] = (v16f)0.0f; acc[0][1] = (v16f)0.0f;
    acc[1][0] = (v16f)0.0f; acc[1][1] = (v16f)0.0f;

    {
        v8h A0, A1, A2, A3, N0, N1, N2, N3;
        v2h svC, svN;
        A0 = *(const v8h*)(Wb1);        A1 = *(const v8h*)(Wb1 + 512);
        A2 = *(const v8h*)(Wb1 + 2048); A3 = *(const v8h*)(Wb1 + 2560);
        svC = *(const v2h*)(hPp);       // h = 0
        #pragma unroll 1
        for (int i = 0; i < 64; ++i) {
            const int kn = (i + 1) & 63;
            const _Float16* Wn = Wb1 + (size_t)kn * 4096;
            N0 = *(const v8h*)(Wn);        N1 = *(const v8h*)(Wn + 512);
            N2 = *(const v8h*)(Wn + 2048); N3 = *(const v8h*)(Wn + 2560);
            svN = *(const v2h*)(hPp + kn * 64);
            _Float16 s0 = svC[0], s1 = svC[1];
            v8h s08 = {s0, s0, s0, s0, s0, s0, s0, s0};
            v8h s18 = {s1, s1, s1, s1, s1, s1, s1, s1};
            v8h be0 = s08 * xw[0][0];
            v8h be1 = s18 * xw[1][0];
            acc[0][0] = mfma32(A0, be0, acc[0][0]);
            acc[1][0] = mfma32(A1, be0, acc[1][0]);
            acc[0][1] = mfma32(A0, be1, acc[0][1]);
            acc[1][1] = mfma32(A1, be1, acc[1][1]);
            v8h bo0 = s08 * xw[0][1];
            v8h bo1 = s18 * xw[1][1];
            acc[0][0] = mfma32(A2, bo0, acc[0][0]);
            acc[1][0] = mfma32(A3, bo0, acc[1][0]);
            acc[0][1] = mfma32(A2, bo1, acc[0][1]);
            acc[1][1] = mfma32(A3, bo1, acc[1][1]);
            A0 = N0; A1 = N1; A2 = N2; A3 = N3;
            svC = svN;
        }
    }

    // ---- epilogue 1: wave's 64 rows -> out[b, 64+o] ----
    #pragma unroll
    for (int sl = 0; sl < 2; ++sl) {
        #pragma unroll
        for (int reg = 0; reg < 16; ++reg) {
            const int o = rh * 64 + sl * 32 + (reg & 3) + 8 * (reg >> 2) + 4 * hi;
            const float bias = b1[o];
            float v0 = acc[sl][0][reg] + bias; v0 = v0 > 0.0f ? v0 : 0.0f;
            float v1 = acc[sl][1][reg] + bias; v1 = v1 > 0.0f ? v1 : 0.0f;
            float s = v0 + v1;
            s += __shfl_xor(s, 1);
            s += __shfl_xor(s, 2);
            s += __shfl_xor(s, 4);
            s += __shfl_xor(s, 8);
            s += __shfl_xor(s, 16);
            if (d0 == 0) out[(size_t)(b0i + p) * OUTC + 64 + o] = s;
        }
    }
}

extern "C" void kernel_launch(void* const* d_in, const int* in_sizes, int n_in,
                              void* d_out, int out_size, void* d_ws, size_t ws_size,
                              hipStream_t stream) {
    const float* X  = (const float*)d_in[0];
    const float* W0 = (const float*)d_in[1];
    const float* b0 = (const float*)d_in[2];
    const float* W1 = (const float*)d_in[3];
    const float* b1 = (const float*)d_in[4];
    float* out = (float*)d_out;
    _Float16* wsw = (_Float16*)d_ws;  // needs 768 KB

    convert_w_kernel<<<(CVT_THREADS + 255) / 256, 256, 0, stream>>>(W0, W1, wsw);
    cin_kernel<<<BATCH / 2, 256, 0, stream>>>(X, b0, b1, wsw, out);
}

// Round 12
// 149.800 us; speedup vs baseline: 1.1917x; 1.1917x over previous
//
#include <hip/hip_runtime.h>

// CIN forward: B=2048, F=32, DIM=64, layers (128,128)
// out[b, 0:64]   = sum_d relu(W0 @ z0 + b0)[64:128, d]
// out[b, 64:192] = sum_d relu(W1 @ z1 + b1)[0:128, d]
// z0[h*32+m, d] = x[h,d]*x[m,d]   (h,m in [0,32))
// z1[h*32+m, d] = h1[h,d]*x[m,d]  (h in [0,64), m in [0,32)), h1 = layer0 rows 0..63
//
// R12: exact R5c shell (best measured: cin 84.4us) + ONE variable: s_setprio
// around each 16-MFMA cluster. R11 failed correctness (asm loads forced VGPR
// overpressure -> spill of in-flight load dests); that axis is closed. m114:
// MFMA/VALU are separate pipes -> the 45% MFMA idle is wave phase-correlation,
// the regime where T5 helps free-running structures (attn +4-7%, m191). R7
// contained setprio but was confounded by its occupancy collapse (VGPR 84);
// here launch_bounds(256,4) guards the register budget (R5c proved VGPR=64).
//
// A-frag swizzle (16x16x32): wsw[ks*4096 + s*512 + lane*8 + j]
//   = W[(s*16 + (lane&15))*K + ks*32 + (lane>>4)*8 + j]

#define BATCH 2048
#define FSZ   32
#define DIM   64
#define K0    1024
#define K1    2048
#define OUTC  192

#define W0_ELEMS (128 * K0)            // 131072 f16
#define W1_ELEMS (128 * K1)            // 262144 f16
#define TOT_ELEMS (W0_ELEMS + W1_ELEMS)
#define CVT_THREADS (TOT_ELEMS / 4)    // 98304 -> 384 blocks

typedef _Float16 v8h __attribute__((ext_vector_type(8)));
typedef _Float16 v4h __attribute__((ext_vector_type(4)));
typedef float    v4f __attribute__((ext_vector_type(4)));

#define XT_PITCH 40   // xT[d][m]: 80B rows, 16B-aligned v8h loads

// One thread per 4 output f16: coalesced 8B stores, aligned float4 reads.
__global__ void convert_w_kernel(const float* __restrict__ W0,
                                 const float* __restrict__ W1,
                                 _Float16* __restrict__ wsw) {
    int t = blockIdx.x * blockDim.x + threadIdx.x;
    if (t >= CVT_THREADS) return;
    int e = t * 4;
    const float* src;
    _Float16* dst;
    if (e < W0_ELEMS) {
        int j0 = e & 7, lane = (e >> 3) & 63, s = (e >> 9) & 7, ks = e >> 12;
        src = W0 + (size_t)(s * 16 + (lane & 15)) * K0
                 + ks * 32 + (lane >> 4) * 8 + j0;
        dst = wsw + e;
    } else {
        int u = e - W0_ELEMS;
        int j0 = u & 7, lane = (u >> 3) & 63, s = (u >> 9) & 7, ks = u >> 12;
        src = W1 + (size_t)(s * 16 + (lane & 15)) * K1
                 + ks * 32 + (lane >> 4) * 8 + j0;
        dst = wsw + W0_ELEMS + u;
    }
    float4 v = *(const float4*)src;
    dst[0] = (_Float16)v.x;
    dst[1] = (_Float16)v.y;
    dst[2] = (_Float16)v.z;
    dst[3] = (_Float16)v.w;
}

__global__ __launch_bounds__(256, 4) void cin_kernel(
    const float* __restrict__ X,      // (B, 32, 64) fp32
    const float* __restrict__ b0,     // (128,)
    const float* __restrict__ b1,     // (128,)
    const _Float16* __restrict__ Wsw, // swizzled W0 then W1 (f16)
    float* __restrict__ out)          // (B, 192) fp32
{
    __shared__ _Float16 xT[2][DIM * XT_PITCH];   // xT[p][d][m]      (10240 B)
    __shared__ _Float16 xS[2][FSZ * 64];         // xS[p][m][c*4+t]  ( 8192 B)
    __shared__ _Float16 h1S[2][64 * 64];         // h1S[p][h][c*4+t] (16384 B)

    const int b0i  = blockIdx.x * 2;
    const int tid  = threadIdx.x;
    const int wave = tid >> 6;
    const int lane = tid & 63;
    const int p    = wave & 1;        // batch member
    const int rh   = wave >> 1;       // row half (64 rows)
    const int quad = lane >> 4;
    const int col  = lane & 15;

    // ---- stage both batches' x -> LDS (both layouts, f16) ----
    #pragma unroll
    for (int i = 0; i < 4; ++i) {
        int idx = tid + i * 256;               // float4 index 0..1023
        int pp = idx >> 9, r4 = idx & 511;
        float4 v = *(const float4*)(X + (size_t)(b0i + pp) * (FSZ * DIM) + r4 * 4);
        int m = (r4 * 4) >> 6, d = (r4 * 4) & 63;
        int tq = d >> 4, cc = d & 15;          // constant within the float4
        _Float16 f0 = (_Float16)v.x, f1 = (_Float16)v.y,
                 f2 = (_Float16)v.z, f3 = (_Float16)v.w;
        xT[pp][(d + 0) * XT_PITCH + m] = f0;
        xT[pp][(d + 1) * XT_PITCH + m] = f1;
        xT[pp][(d + 2) * XT_PITCH + m] = f2;
        xT[pp][(d + 3) * XT_PITCH + m] = f3;
        xS[pp][m * 64 + (cc + 0) * 4 + tq] = f0;
        xS[pp][m * 64 + (cc + 1) * 4 + tq] = f1;
        xS[pp][m * 64 + (cc + 2) * 4 + tq] = f2;
        xS[pp][m * 64 + (cc + 3) * 4 + tq] = f3;
    }
    __syncthreads();

    // K-invariant x parts of B fragments: xv8[t][j] = x[quad*8+j][16t+col]
    v8h xv8[4];
    #pragma unroll
    for (int t = 0; t < 4; ++t)
        xv8[t] = *(const v8h*)(&xT[p][(16 * t + col) * XT_PITCH + quad * 8]);

    const _Float16* WbL0 = Wsw + (size_t)rh * 2048 + (size_t)lane * 8;  // via rh*4 streams
    const _Float16* Wb   = Wsw + (size_t)(rh * 4) * 512 + (size_t)lane * 8;
    const _Float16* xSp  = &xS[p][col * 4];
    const _Float16* h1Sp = &h1S[p][col * 4];
    (void)WbL0;

    // ================= layer 0 =================
    v4f acc[4][4];
    #pragma unroll
    for (int f = 0; f < 4; ++f)
        #pragma unroll
        for (int t = 0; t < 4; ++t) acc[f][t] = (v4f)0.0f;

    {
        v8h aC[4], aN[4];
        v4h svC, svN;
        #pragma unroll
        for (int i = 0; i < 4; ++i) aC[i] = *(const v8h*)(Wb + i * 512);
        svC = *(const v4h*)(xSp);
        #pragma unroll 2
        for (int ks = 0; ks < 32; ++ks) {
            // clamped prefetch: last iter re-reads step 0 (valid, unused)
            const int kn = (ks + 1) & 31;
            const _Float16* Wn = Wb + (size_t)kn * 4096;
            #pragma unroll
            for (int i = 0; i < 4; ++i) aN[i] = *(const v8h*)(Wn + i * 512);
            svN = *(const v4h*)(xSp + kn * 64);
            __builtin_amdgcn_s_setprio(1);
            #pragma unroll
            for (int t = 0; t < 4; ++t) {
                _Float16 s = svC[t];
                v8h s8 = {s, s, s, s, s, s, s, s};
                v8h bfr = s8 * xv8[t];
                acc[0][t] = __builtin_amdgcn_mfma_f32_16x16x32_f16(aC[0], bfr, acc[0][t], 0, 0, 0);
                acc[1][t] = __builtin_amdgcn_mfma_f32_16x16x32_f16(aC[1], bfr, acc[1][t], 0, 0, 0);
                acc[2][t] = __builtin_amdgcn_mfma_f32_16x16x32_f16(aC[2], bfr, acc[2][t], 0, 0, 0);
                acc[3][t] = __builtin_amdgcn_mfma_f32_16x16x32_f16(aC[3], bfr, acc[3][t], 0, 0, 0);
            }
            __builtin_amdgcn_s_setprio(0);
            #pragma unroll
            for (int i = 0; i < 4; ++i) aC[i] = aN[i];
            svC = svN;
        }
    }

    // ---- epilogue 0 ----
    // rh=0: rows 0..63 -> h1S[p] (packed v4h writes); rh=1: rows 64..127 -> out
    if (rh == 0) {
        #pragma unroll
        for (int f = 0; f < 4; ++f) {
            #pragma unroll
            for (int reg = 0; reg < 4; ++reg) {
                const int o = f * 16 + quad * 4 + reg;
                const float bias = b0[o];
                v4h pk;
                #pragma unroll
                for (int t = 0; t < 4; ++t) {
                    float v = acc[f][t][reg] + bias;
                    v = v > 0.0f ? v : 0.0f;
                    pk[t] = (_Float16)v;
                }
                *(v4h*)(&h1S[p][o * 64 + col * 4]) = pk;
            }
        }
    } else {
        #pragma unroll
        for (int f = 0; f < 4; ++f) {
            #pragma unroll
            for (int reg = 0; reg < 4; ++reg) {
                const int o = 64 + f * 16 + quad * 4 + reg;
                const float bias = b0[o];
                float s = 0.0f;
                #pragma unroll
                for (int t = 0; t < 4; ++t) {
                    float v = acc[f][t][reg] + bias;
                    s += (v > 0.0f ? v : 0.0f);
                }
                s += __shfl_xor(s, 1);
                s += __shfl_xor(s, 2);
                s += __shfl_xor(s, 4);
                s += __shfl_xor(s, 8);
                if (col == 0) out[(size_t)(b0i + p) * OUTC + (o - 64)] = s;
            }
        }
    }
    __syncthreads();   // h1S visible to all waves

    // ================= layer 1 =================
    #pragma unroll
    for (int f = 0; f < 4; ++f)
        #pragma unroll
        for (int t = 0; t < 4; ++t) acc[f][t] = (v4f)0.0f;

    {
        const _Float16* Wb1 = Wsw + W0_ELEMS + (size_t)(rh * 4) * 512 + (size_t)lane * 8;
        v8h aC[4], aN[4];
        v4h svC, svN;
        #pragma unroll
        for (int i = 0; i < 4; ++i) aC[i] = *(const v8h*)(Wb1 + i * 512);
        svC = *(const v4h*)(h1Sp);
        #pragma unroll 2
        for (int ks = 0; ks < 64; ++ks) {
            const int kn = (ks + 1) & 63;
            const _Float16* Wn = Wb1 + (size_t)kn * 4096;
            #pragma unroll
            for (int i = 0; i < 4; ++i) aN[i] = *(const v8h*)(Wn + i * 512);
            svN = *(const v4h*)(h1Sp + kn * 64);
            __builtin_amdgcn_s_setprio(1);
            #pragma unroll
            for (int t = 0; t < 4; ++t) {
                _Float16 s = svC[t];
                v8h s8 = {s, s, s, s, s, s, s, s};
                v8h bfr = s8 * xv8[t];
                acc[0][t] = __builtin_amdgcn_mfma_f32_16x16x32_f16(aC[0], bfr, acc[0][t], 0, 0, 0);
                acc[1][t] = __builtin_amdgcn_mfma_f32_16x16x32_f16(aC[1], bfr, acc[1][t], 0, 0, 0);
                acc[2][t] = __builtin_amdgcn_mfma_f32_16x16x32_f16(aC[2], bfr, acc[2][t], 0, 0, 0);
                acc[3][t] = __builtin_amdgcn_mfma_f32_16x16x32_f16(aC[3], bfr, acc[3][t], 0, 0, 0);
            }
            __builtin_amdgcn_s_setprio(0);
            #pragma unroll
            for (int i = 0; i < 4; ++i) aC[i] = aN[i];
            svC = svN;
        }
    }

    // ---- epilogue 1: wave's 64 rows -> out[b, 64+o] ----
    #pragma unroll
    for (int f = 0; f < 4; ++f) {
        #pragma unroll
        for (int reg = 0; reg < 4; ++reg) {
            const int o = rh * 64 + f * 16 + quad * 4 + reg;
            const float bias = b1[o];
            float s = 0.0f;
            #pragma unroll
            for (int t = 0; t < 4; ++t) {
                float v = acc[f][t][reg] + bias;
                s += (v > 0.0f ? v : 0.0f);
            }
            s += __shfl_xor(s, 1);
            s += __shfl_xor(s, 2);
            s += __shfl_xor(s, 4);
            s += __shfl_xor(s, 8);
            if (col == 0) out[(size_t)(b0i + p) * OUTC + 64 + o] = s;
        }
    }
}

extern "C" void kernel_launch(void* const* d_in, const int* in_sizes, int n_in,
                              void* d_out, int out_size, void* d_ws, size_t ws_size,
                              hipStream_t stream) {
    const float* X  = (const float*)d_in[0];
    const float* W0 = (const float*)d_in[1];
    const float* b0 = (const float*)d_in[2];
    const float* W1 = (const float*)d_in[3];
    const float* b1 = (const float*)d_in[4];
    float* out = (float*)d_out;
    _Float16* wsw = (_Float16*)d_ws;  // needs 768 KB

    convert_w_kernel<<<(CVT_THREADS + 255) / 256, 256, 0, stream>>>(W0, W1, wsw);
    cin_kernel<<<BATCH / 2, 256, 0, stream>>>(X, b0, b1, wsw, out);
}